// Round 3
// baseline (24.231 us; speedup 1.0000x reference)
//
#include <hip/hip_runtime.h>

#define MAX_NODE 511
#define SLOTS (MAX_NODE + 1)   // 512
#define CDIM 1024              // channels (f32)

typedef float f32x4 __attribute__((ext_vector_type(4)));

// One block per output row (b, slot). 256 threads x float4 = 1024 floats = 4 KiB row.
// Offsets computed per-wave via shfl reduction (no LDS, no syncthreads).
__global__ __launch_bounds__(256)
void graph_embed_kernel(const float* __restrict__ patch,   // [total_nodes, CDIM]
                        const float* __restrict__ cent,    // [total_nodes, 2]
                        const float* __restrict__ img,     // [B, CDIM]
                        const int*   __restrict__ nn,      // [B]
                        float* __restrict__ out, int B) {
    const int bid  = blockIdx.x;
    const int b    = bid >> 9;        // / SLOTS
    const int slot = bid & (SLOTS - 1);
    const int t    = threadIdx.x;
    const int lane = t & 63;

    // Wave-parallel exclusive prefix: off = sum(nn[0..b-1]), n = nn[b].
    // B <= 64 (B=32 here): one coalesced load per wave, 6 shfl_xor steps.
    int v = (lane < B) ? nn[lane] : 0;
    const int n = __shfl(v, b, 64);
    int c = (lane < b) ? v : 0;
    #pragma unroll
    for (int d = 1; d < 64; d <<= 1) c += __shfl_xor(c, d, 64);
    const int off   = c;
    const int n_eff = (n < MAX_NODE) ? n : MAX_NODE;

    float* features = out;
    float* mask     = out + (size_t)B * SLOTS * CDIM;
    float* pos_x    = mask  + (size_t)B * SLOTS;
    float* pos_y    = pos_x + (size_t)B * SLOTS;

    f32x4 vv;
    if (slot == 0) {
        vv = *(reinterpret_cast<const f32x4*>(img + (size_t)b * CDIM) + t);
    } else {
        const int j = slot - 1;
        if (j < n_eff) {
            vv = __builtin_nontemporal_load(
                reinterpret_cast<const f32x4*>(patch + (size_t)(off + j) * CDIM) + t);
        } else {
            vv = (f32x4)(0.f);
        }
    }
    __builtin_nontemporal_store(
        vv, reinterpret_cast<f32x4*>(features + ((size_t)b * SLOTS + slot) * CDIM) + t);

    if (t == 0) {
        const float m = (slot >= n + 1 && n <= MAX_NODE) ? 1.0f : 0.0f;
        float px = 0.f, py = 0.f;
        if (slot >= 1) {
            const int j = slot - 1;
            if (j < n_eff) {
                px = cent[(size_t)(off + j) * 2 + 0];
                py = cent[(size_t)(off + j) * 2 + 1];
            }
        }
        const size_t mi = (size_t)b * SLOTS + slot;
        mask[mi]  = m;
        pos_x[mi] = px;
        pos_y[mi] = py;
    }
}

extern "C" void kernel_launch(void* const* d_in, const int* in_sizes, int n_in,
                              void* d_out, int out_size, void* d_ws, size_t ws_size,
                              hipStream_t stream) {
    const float* patch = (const float*)d_in[0];   // [total_nodes, 1024]
    const float* cent  = (const float*)d_in[1];   // [total_nodes, 2]
    const float* img   = (const float*)d_in[2];   // [B, 1024]
    const int*   nn    = (const int*)d_in[3];     // [B]
    float* out = (float*)d_out;

    const int B = in_sizes[3];
    const int nblocks = B * SLOTS;
    graph_embed_kernel<<<nblocks, 256, 0, stream>>>(patch, cent, img, nn, out, B);
}

// Round 4
// 19.815 us; speedup vs baseline: 1.2229x; 1.2229x over previous
//
#include <hip/hip_runtime.h>

#define MAX_NODE 511
#define SLOTS (MAX_NODE + 1)   // 512
#define CDIM 1024              // channels (f32)
#define RPB 4                  // rows per block (SLOTS % RPB == 0)

typedef float f32x4 __attribute__((ext_vector_type(4)));

// Grid: (B*SLOTS/RPB) blocks x 256 threads. Each block handles RPB consecutive
// output rows (same b, since SLOTS % RPB == 0): 4 independent 4 KiB load->store
// chains per wave for MLP. Offsets via wave-parallel shfl prefix (B <= 64).
__global__ __launch_bounds__(256)
void graph_embed_kernel(const float* __restrict__ patch,   // [total_nodes, CDIM]
                        const float* __restrict__ cent,    // [total_nodes, 2]
                        const float* __restrict__ img,     // [B, CDIM]
                        const int*   __restrict__ nn,      // [B]
                        float* __restrict__ out, int B) {
    const int rb    = blockIdx.x * RPB;   // first flattened row (b*SLOTS + slot)
    const int b     = rb >> 9;            // / SLOTS
    const int slot0 = rb & (SLOTS - 1);
    const int t     = threadIdx.x;
    const int lane  = t & 63;

    // Wave-parallel exclusive prefix: off = sum(nn[0..b-1]), n = nn[b].
    int v = (lane < B) ? nn[lane] : 0;
    const int n = __shfl(v, b, 64);
    int c = (lane < b) ? v : 0;
    #pragma unroll
    for (int d = 1; d < 64; d <<= 1) c += __shfl_xor(c, d, 64);
    const int off   = c;
    const int n_eff = (n < MAX_NODE) ? n : MAX_NODE;

    float* features = out;
    float* mask     = out + (size_t)B * SLOTS * CDIM;
    float* pos_x    = mask  + (size_t)B * SLOTS;
    float* pos_y    = pos_x + (size_t)B * SLOTS;

    const f32x4* patch4 = reinterpret_cast<const f32x4*>(patch);
    const f32x4* img4   = reinterpret_cast<const f32x4*>(img);
    f32x4*       feat4  = reinterpret_cast<f32x4*>(features);

    // Issue RPB independent loads, then RPB stores.
    f32x4 r[RPB];
    #pragma unroll
    for (int k = 0; k < RPB; ++k) {
        const int slot = slot0 + k;
        if (slot == 0) {
            r[k] = img4[(size_t)b * (CDIM / 4) + t];
        } else {
            const int j = slot - 1;
            if (j < n_eff) {
                r[k] = patch4[(size_t)(off + j) * (CDIM / 4) + t];
            } else {
                r[k] = (f32x4)(0.f);
            }
        }
    }
    #pragma unroll
    for (int k = 0; k < RPB; ++k) {
        feat4[((size_t)b * SLOTS + slot0 + k) * (CDIM / 4) + t] = r[k];
    }

    // mask / pos: threads 0..RPB-1 each handle one row (consecutive dwords).
    if (t < RPB) {
        const int slot = slot0 + t;
        const float m = (slot >= n + 1 && n <= MAX_NODE) ? 1.0f : 0.0f;
        float px = 0.f, py = 0.f;
        if (slot >= 1) {
            const int j = slot - 1;
            if (j < n_eff) {
                px = cent[(size_t)(off + j) * 2 + 0];
                py = cent[(size_t)(off + j) * 2 + 1];
            }
        }
        const size_t mi = (size_t)b * SLOTS + slot;
        mask[mi]  = m;
        pos_x[mi] = px;
        pos_y[mi] = py;
    }
}

extern "C" void kernel_launch(void* const* d_in, const int* in_sizes, int n_in,
                              void* d_out, int out_size, void* d_ws, size_t ws_size,
                              hipStream_t stream) {
    const float* patch = (const float*)d_in[0];   // [total_nodes, 1024]
    const float* cent  = (const float*)d_in[1];   // [total_nodes, 2]
    const float* img   = (const float*)d_in[2];   // [B, 1024]
    const int*   nn    = (const int*)d_in[3];     // [B]
    float* out = (float*)d_out;

    const int B = in_sizes[3];
    const int nblocks = (B * SLOTS) / RPB;
    graph_embed_kernel<<<nblocks, 256, 0, stream>>>(patch, cent, img, nn, out, B);
}